// Round 3
// baseline (176.107 us; speedup 1.0000x reference)
//
#include <hip/hip_runtime.h>
#include <hip/hip_bf16.h>

#define NB 8192
#define ND 1024
#define NE 8
#define BSTRIDE 2048   // bucket capacity per expert (counts ~1024±30, 2x margin)

typedef unsigned short u16;
typedef __bf16 bf16x8 __attribute__((ext_vector_type(8)));
typedef float f32x4 __attribute__((ext_vector_type(4)));
typedef u16 u16x8 __attribute__((ext_vector_type(8)));
typedef u16 u16x4 __attribute__((ext_vector_type(4)));

__device__ __forceinline__ u16 f2bf(float f) {
    union { float f; unsigned u; } v; v.f = f;
    unsigned r = v.u + 0x7fffu + ((v.u >> 16) & 1u);
    return (u16)(r >> 16);
}

// ---------------- K1 fused: X cvt (4096 blocks) + W1 cvt/transpose (2048) + prep (32) ----------------
__global__ __launch_bounds__(256) void k_pre(
    const float* __restrict__ X, u16* __restrict__ Xb,
    const float* __restrict__ W1, u16* __restrict__ W1t,
    const int* __restrict__ ids, const float* __restrict__ b2,
    float* __restrict__ out, int* __restrict__ counts, int* __restrict__ bucket)
{
    int bid = blockIdx.x;
    int t = threadIdx.x;
    if (bid < 4096) {
        // X fp32 -> bf16
        long i = ((long)bid * 256 + t) * 8;
        f32x4 a = *(const f32x4*)(X + i);
        f32x4 b = *(const f32x4*)(X + i + 4);
        u16x8 o;
        o[0] = f2bf(a[0]); o[1] = f2bf(a[1]); o[2] = f2bf(a[2]); o[3] = f2bf(a[3]);
        o[4] = f2bf(b[0]); o[5] = f2bf(b[1]); o[6] = f2bf(b[2]); o[7] = f2bf(b[3]);
        *(u16x8*)(Xb + i) = o;
        return;
    }
    if (bid < 6144) {
        // W1 [e][k][n] fp32 -> W1t [e][n][k] bf16 via 64x64 LDS transpose
        __shared__ float s[64][65];
        int bid2 = bid - 4096;
        int e = bid2 >> 8;
        int tr = ((bid2 >> 4) & 15) << 6;  // k tile base
        int tc = (bid2 & 15) << 6;         // n tile base
        const float* src = W1 + (size_t)e * ND * ND;
        u16* dst = W1t + (size_t)e * ND * ND;
        #pragma unroll
        for (int i = 0; i < 4; ++i) {
            int idx = i * 256 + t;
            int r = idx >> 4, c4 = (idx & 15) * 4;
            f32x4 v = *(const f32x4*)(src + (size_t)(tr + r) * ND + tc + c4);
            s[c4 + 0][r] = v[0]; s[c4 + 1][r] = v[1];
            s[c4 + 2][r] = v[2]; s[c4 + 3][r] = v[3];
        }
        __syncthreads();
        #pragma unroll
        for (int i = 0; i < 4; ++i) {
            int idx = i * 256 + t;
            int n = idx >> 4, k4 = (idx & 15) * 4;
            u16x4 o;
            o[0] = f2bf(s[n][k4 + 0]); o[1] = f2bf(s[n][k4 + 1]);
            o[2] = f2bf(s[n][k4 + 2]); o[3] = f2bf(s[n][k4 + 3]);
            *(u16x4*)(dst + (size_t)(tc + n) * ND + tr + k4) = o;
        }
        return;
    }
    // prep: bucket samples by expert (wave-ballot scatter), init out with b2
    int b = (bid - 6144) * 256 + t;
    int e = ids[b];
    out[2 * b]     = b2[2 * e];
    out[2 * b + 1] = b2[2 * e + 1];
    int lane = t & 63;
    unsigned long long lt = (1ull << lane) - 1ull;
    int pos = 0;
    #pragma unroll
    for (int ee = 0; ee < NE; ++ee) {
        unsigned long long m = __ballot(e == ee);
        if (m) {
            int leader = __ffsll((long long)m) - 1;
            int r = __popcll(m & lt);
            int base = 0;
            if (e == ee && r == 0) base = atomicAdd(&counts[ee], __popcll(m));
            base = __shfl(base, leader, 64);
            if (e == ee) pos = base + r;
        }
    }
    bucket[e * BSTRIDE + pos] = b;
}

// ---------------- K2: grouped GEMM 64x128 tile (bf16 MFMA) + fused layer-2 epilogue ----------------
#define GLDS16(src, dst) __builtin_amdgcn_global_load_lds( \
    (const __attribute__((address_space(1))) void*)(src), \
    (__attribute__((address_space(3))) void*)(dst), 16, 0, 0)

__global__ __launch_bounds__(256) void k_gemm(
    const u16* __restrict__ Xb, const u16* __restrict__ W1t,
    const float* __restrict__ b1, const float* __restrict__ W2,
    const int* __restrict__ counts, const int* __restrict__ bucket,
    float* __restrict__ out)
{
    __shared__ u16 sA[2][2048];   // 64 x 32 per buffer
    __shared__ u16 sB[2][4096];   // 128 x 32 per buffer
    __shared__ int sRows[64];

    int bid = blockIdx.x;
    int e  = bid & 7;          // expert fastest -> pinned per-XCD L2
    int nt = (bid >> 3) & 7;
    int mt = bid >> 6;         // 0..31

    int cnt = counts[e];
    if (mt * 64 >= cnt) return;
    int rem = cnt - mt * 64;

    int t = threadIdx.x;
    if (t < 64) {
        int r = mt * 64 + t;
        sRows[t] = bucket[e * BSTRIDE + (r < cnt ? r : 0)];
    }
    __syncthreads();

    int n0 = nt * 128;
    int ar = t >> 2, as = (t & 3) * 8;   // 16B chunk layout: row=chunk>>2
    const u16* ap  = Xb + (size_t)sRows[ar] * ND + as;
    const u16* b0p = W1t + ((size_t)e * ND + n0 + ar) * ND + as;
    const u16* b1p = W1t + ((size_t)e * ND + n0 + 64 + ar) * ND + as;
    int w = t >> 6;
    int l = t & 63;
    int lc = l & 15, kg = l >> 4;
    int wm = (w >> 1) * 32, wn = (w & 1) * 64;

    f32x4 acc[2][4] = {};

    char* A0 = (char*)sA;
    char* B0 = (char*)sB;

    auto stage = [&](int buf, int kt) {
        int k0 = kt * 32;
        GLDS16(ap  + k0, A0 + buf * 4096 + w * 1024);
        GLDS16(b0p + k0, B0 + buf * 8192 + w * 1024);
        GLDS16(b1p + k0, B0 + buf * 8192 + 4096 + w * 1024);
    };

    stage(0, 0);

    #pragma unroll 2
    for (int kt = 0; kt < 32; ++kt) {
        int buf = kt & 1;
        if (kt + 1 < 32) {
            stage(buf ^ 1, kt + 1);
            asm volatile("s_waitcnt vmcnt(3)" ::: "memory");
        } else {
            asm volatile("s_waitcnt vmcnt(0)" ::: "memory");
        }
        asm volatile("s_barrier" ::: "memory");

        const char* Ab = A0 + buf * 4096;
        const char* Bb = B0 + buf * 8192;
        bf16x8 af[2], bfr[4];
        #pragma unroll
        for (int mf = 0; mf < 2; ++mf)
            af[mf] = *(const bf16x8*)(Ab + (wm + mf * 16 + lc) * 64 + kg * 16);
        #pragma unroll
        for (int nf = 0; nf < 4; ++nf)
            bfr[nf] = *(const bf16x8*)(Bb + (wn + nf * 16 + lc) * 64 + kg * 16);
        #pragma unroll
        for (int mf = 0; mf < 2; ++mf) {
            #pragma unroll
            for (int nf = 0; nf < 4; ++nf)
                acc[mf][nf] = __builtin_amdgcn_mfma_f32_16x16x32_bf16(af[mf], bfr[nf], acc[mf][nf], 0, 0, 0);
        }
        asm volatile("s_barrier" ::: "memory");
    }

    // fused layer 2: logits[b] += sum_n relu(h + b1) * W2[e][n][:]
    float b1v[4], w20[4], w21[4];
    #pragma unroll
    for (int nf = 0; nf < 4; ++nf) {
        int ncol = n0 + wn + nf * 16 + lc;
        b1v[nf] = b1[e * ND + ncol];
        w20[nf] = W2[((size_t)e * ND + ncol) * 2 + 0];
        w21[nf] = W2[((size_t)e * ND + ncol) * 2 + 1];
    }
    #pragma unroll
    for (int mf = 0; mf < 2; ++mf) {
        #pragma unroll
        for (int r = 0; r < 4; ++r) {
            float s0 = 0.f, s1 = 0.f;
            #pragma unroll
            for (int nf = 0; nf < 4; ++nf) {
                float h = acc[mf][nf][r] + b1v[nf];
                h = fmaxf(h, 0.f);
                s0 += h * w20[nf];
                s1 += h * w21[nf];
            }
            #pragma unroll
            for (int m = 8; m >= 1; m >>= 1) {
                s0 += __shfl_xor(s0, m, 64);
                s1 += __shfl_xor(s1, m, 64);
            }
            int row = wm + mf * 16 + kg * 4 + r;
            if (lc == 0 && row < rem) {
                int b = sRows[row];
                atomicAdd(&out[2 * b], s0);
                atomicAdd(&out[2 * b + 1], s1);
            }
        }
    }
}

extern "C" void kernel_launch(void* const* d_in, const int* in_sizes, int n_in,
                              void* d_out, int out_size, void* d_ws, size_t ws_size,
                              hipStream_t stream)
{
    const float* X   = (const float*)d_in[0];
    const int*   ids = (const int*)d_in[1];
    const float* W1  = (const float*)d_in[2];
    const float* b1  = (const float*)d_in[3];
    const float* W2  = (const float*)d_in[4];
    const float* b2  = (const float*)d_in[5];
    float* out = (float*)d_out;

    char* ws = (char*)d_ws;
    int* counts = (int*)ws;                       // 32 B
    int* bucket = (int*)(ws + 4096);              // 8 * 2048 * 4 = 64 KB
    u16* Xb     = (u16*)(ws + 131072);            // 16 MB
    u16* W1t    = (u16*)(ws + 131072 + (size_t)NB * ND * 2);  // 16 MB

    hipMemsetAsync(counts, 0, NE * sizeof(int), stream);
    k_pre<<<4096 + 2048 + 32, 256, 0, stream>>>(X, Xb, W1, W1t, ids, b2, out, counts, bucket);
    k_gemm<<<32 * 64, 256, 0, stream>>>(Xb, W1t, b1, W2, counts, bucket, out);
}

// Round 4
// 173.339 us; speedup vs baseline: 1.0160x; 1.0160x over previous
//
#include <hip/hip_runtime.h>
#include <hip/hip_bf16.h>

#define NB 8192
#define ND 1024
#define NE 8
#define BSTRIDE 2048   // bucket capacity per expert
#define MTMAX 18       // max 64-row tiles per expert (cnt ~1024±30)

typedef unsigned short u16;
typedef __bf16 bf16x8 __attribute__((ext_vector_type(8)));
typedef float f32x4 __attribute__((ext_vector_type(4)));
typedef u16 u16x8 __attribute__((ext_vector_type(8)));
typedef u16 u16x4 __attribute__((ext_vector_type(4)));

__device__ __forceinline__ u16 f2bf(float f) {
    union { float f; unsigned u; } v; v.f = f;
    unsigned r = v.u + 0x7fffu + ((v.u >> 16) & 1u);
    return (u16)(r >> 16);
}

// ---------------- K0: bucket by expert (ballot scatter) + init out with b2 ----------------
__global__ __launch_bounds__(256) void k_prep(const int* __restrict__ ids,
    const float* __restrict__ b2, float* __restrict__ out,
    int* __restrict__ counts, int* __restrict__ bucket)
{
    int t = threadIdx.x;
    int b = blockIdx.x * 256 + t;
    int e = ids[b];
    out[2 * b]     = b2[2 * e];
    out[2 * b + 1] = b2[2 * e + 1];
    int lane = t & 63;
    unsigned long long lt = (1ull << lane) - 1ull;
    int pos = 0;
    #pragma unroll
    for (int ee = 0; ee < NE; ++ee) {
        unsigned long long m = __ballot(e == ee);
        if (m) {
            int leader = __ffsll((long long)m) - 1;
            int r = __popcll(m & lt);
            int base = 0;
            if (e == ee && r == 0) base = atomicAdd(&counts[ee], __popcll(m));
            base = __shfl(base, leader, 64);
            if (e == ee) pos = base + r;
        }
    }
    bucket[e * BSTRIDE + pos] = b;
}

// ---------------- K1: pack W1 -> W1p tiles  AND  X -> Ag gathered tiles ----------------
// W1p layout: [e][nt][kt][128 n][32 k] bf16  (8KB chunk per (e,nt,kt))
// Ag  layout: [tile][kt][64 r][32 k] bf16    (4KB chunk per (tile,kt)), tile = tileBase[e]+mt
__global__ __launch_bounds__(256) void k_pack(
    const float* __restrict__ W1, u16* __restrict__ W1p,
    const float* __restrict__ X, u16* __restrict__ Ag,
    const int* __restrict__ counts, const int* __restrict__ bucket)
{
    int bid = blockIdx.x;
    int t = threadIdx.x;
    if (bid < 2048) {
        // W1 [e][k][n] fp32 -> W1p via 64x64 LDS transpose
        __shared__ float s[64][65];
        int e = bid >> 8;
        int tr = ((bid >> 4) & 15) << 6;  // k tile base
        int tc = (bid & 15) << 6;         // n tile base
        const float* src = W1 + (size_t)e * ND * ND;
        #pragma unroll
        for (int i = 0; i < 4; ++i) {
            int idx = i * 256 + t;
            int r = idx >> 4, c4 = (idx & 15) * 4;
            f32x4 v = *(const f32x4*)(src + (size_t)(tr + r) * ND + tc + c4);
            s[c4 + 0][r] = v[0]; s[c4 + 1][r] = v[1];
            s[c4 + 2][r] = v[2]; s[c4 + 3][r] = v[3];
        }
        __syncthreads();
        #pragma unroll
        for (int i = 0; i < 4; ++i) {
            int idx = i * 256 + t;
            int n = idx >> 4, k4 = (idx & 15) * 4;
            int gn = tc + n, gk = tr + k4;
            int nt = gn >> 7, kt = gk >> 5;
            u16x4 o;
            o[0] = f2bf(s[n][k4 + 0]); o[1] = f2bf(s[n][k4 + 1]);
            o[2] = f2bf(s[n][k4 + 2]); o[3] = f2bf(s[n][k4 + 3]);
            *(u16x4*)(W1p + (((size_t)(e * 8 + nt) * 32 + kt) * 4096) + (gn & 127) * 32 + (gk & 31)) = o;
        }
        return;
    }
    // X gather-pack: block = (e, mt, half); 64 rows x 512 k
    __shared__ int sR[64];
    int bid2 = bid - 2048;
    int half = bid2 & 1;
    int g = bid2 >> 1;             // 0..143
    int e = g / MTMAX, mt = g % MTMAX;
    int cnt = counts[e];
    if (mt * 64 >= cnt) return;
    int tb = 0;
    #pragma unroll
    for (int j = 0; j < NE; ++j) if (j < e) tb += (counts[j] + 63) >> 6;
    size_t tbase = (size_t)(tb + mt) * 32 * 2048;
    if (t < 64) {
        int rr = mt * 64 + t;
        sR[t] = bucket[e * BSTRIDE + (rr < cnt ? rr : 0)];
    }
    __syncthreads();
    #pragma unroll 4
    for (int i = 0; i < 32; ++i) {
        int c = i * 256 + t;           // 8192 chunks of 4 fp32
        int r = c >> 7, ck = c & 127;
        int k = half * 512 + ck * 4;
        f32x4 v = *(const f32x4*)(X + (size_t)sR[r] * ND + k);
        u16x4 o;
        o[0] = f2bf(v[0]); o[1] = f2bf(v[1]); o[2] = f2bf(v[2]); o[3] = f2bf(v[3]);
        int kt = k >> 5, ko = k & 31;
        *(u16x4*)(Ag + tbase + (size_t)kt * 2048 + r * 32 + ko) = o;
    }
}

// ---------------- K2: grouped GEMM 64x128 tile (bf16 MFMA) + fused layer-2 epilogue ----------------
#define GLDS16(src, dst) __builtin_amdgcn_global_load_lds( \
    (const __attribute__((address_space(1))) void*)(src), \
    (__attribute__((address_space(3))) void*)(dst), 16, 0, 0)

__global__ __launch_bounds__(256) void k_gemm(
    const u16* __restrict__ Ag, const u16* __restrict__ W1p,
    const float* __restrict__ b1, const float* __restrict__ W2,
    const int* __restrict__ counts, const int* __restrict__ bucket,
    float* __restrict__ out)
{
    __shared__ u16 sA[2][2048];   // 64 x 32 per buffer
    __shared__ u16 sB[2][4096];   // 128 x 32 per buffer
    __shared__ int sRows[64];

    int bid = blockIdx.x;
    int e  = bid & 7;          // expert fastest -> pinned per-XCD L2
    int nt = (bid >> 3) & 7;
    int mt = bid >> 6;         // 0..MTMAX-1

    int cnt = counts[e];
    if (mt * 64 >= cnt) return;
    int rem = cnt - mt * 64;

    int t = threadIdx.x;
    if (t < 64) {
        int r = mt * 64 + t;
        sRows[t] = bucket[e * BSTRIDE + (r < cnt ? r : 0)];
    }
    __syncthreads();

    int tb = 0;
    #pragma unroll
    for (int j = 0; j < NE; ++j) if (j < e) tb += (counts[j] + 63) >> 6;

    int n0 = nt * 128;
    const u16* Abase = Ag + (size_t)(tb + mt) * 32 * 2048 + t * 8;
    const u16* Bbase = W1p + (size_t)(e * 8 + nt) * 32 * 4096 + t * 8;
    int w = t >> 6;
    int l = t & 63;
    int lc = l & 15, kg = l >> 4;
    int wm = (w >> 1) * 32, wn = (w & 1) * 64;

    f32x4 acc[2][4] = {};

    char* A0 = (char*)sA;
    char* B0 = (char*)sB;

    auto stage = [&](int buf, int kt) {
        GLDS16(Abase + (size_t)kt * 2048, A0 + buf * 4096 + w * 1024);
        GLDS16(Bbase + (size_t)kt * 4096, B0 + buf * 8192 + w * 1024);
        GLDS16(Bbase + (size_t)kt * 4096 + 2048, B0 + buf * 8192 + 4096 + w * 1024);
    };

    stage(0, 0);

    #pragma unroll 2
    for (int kt = 0; kt < 32; ++kt) {
        int buf = kt & 1;
        if (kt + 1 < 32) {
            stage(buf ^ 1, kt + 1);
            asm volatile("s_waitcnt vmcnt(3)" ::: "memory");
        } else {
            asm volatile("s_waitcnt vmcnt(0)" ::: "memory");
        }
        asm volatile("s_barrier" ::: "memory");

        const char* Ab = A0 + buf * 4096;
        const char* Bb = B0 + buf * 8192;
        bf16x8 af[2], bfr[4];
        #pragma unroll
        for (int mf = 0; mf < 2; ++mf)
            af[mf] = *(const bf16x8*)(Ab + (wm + mf * 16 + lc) * 64 + kg * 16);
        #pragma unroll
        for (int nf = 0; nf < 4; ++nf)
            bfr[nf] = *(const bf16x8*)(Bb + (wn + nf * 16 + lc) * 64 + kg * 16);
        #pragma unroll
        for (int mf = 0; mf < 2; ++mf) {
            #pragma unroll
            for (int nf = 0; nf < 4; ++nf)
                acc[mf][nf] = __builtin_amdgcn_mfma_f32_16x16x32_bf16(af[mf], bfr[nf], acc[mf][nf], 0, 0, 0);
        }
        asm volatile("s_barrier" ::: "memory");
    }

    // fused layer 2: logits[b] += sum_n relu(h + b1) * W2[e][n][:]
    float b1v[4], w20[4], w21[4];
    #pragma unroll
    for (int nf = 0; nf < 4; ++nf) {
        int ncol = n0 + wn + nf * 16 + lc;
        b1v[nf] = b1[e * ND + ncol];
        w20[nf] = W2[((size_t)e * ND + ncol) * 2 + 0];
        w21[nf] = W2[((size_t)e * ND + ncol) * 2 + 1];
    }
    #pragma unroll
    for (int mf = 0; mf < 2; ++mf) {
        #pragma unroll
        for (int r = 0; r < 4; ++r) {
            float s0 = 0.f, s1 = 0.f;
            #pragma unroll
            for (int nf = 0; nf < 4; ++nf) {
                float h = acc[mf][nf][r] + b1v[nf];
                h = fmaxf(h, 0.f);
                s0 += h * w20[nf];
                s1 += h * w21[nf];
            }
            #pragma unroll
            for (int m = 8; m >= 1; m >>= 1) {
                s0 += __shfl_xor(s0, m, 64);
                s1 += __shfl_xor(s1, m, 64);
            }
            int row = wm + mf * 16 + kg * 4 + r;
            if (lc == 0 && row < rem) {
                int b = sRows[row];
                atomicAdd(&out[2 * b], s0);
                atomicAdd(&out[2 * b + 1], s1);
            }
        }
    }
}

extern "C" void kernel_launch(void* const* d_in, const int* in_sizes, int n_in,
                              void* d_out, int out_size, void* d_ws, size_t ws_size,
                              hipStream_t stream)
{
    const float* X   = (const float*)d_in[0];
    const int*   ids = (const int*)d_in[1];
    const float* W1  = (const float*)d_in[2];
    const float* b1  = (const float*)d_in[3];
    const float* W2  = (const float*)d_in[4];
    const float* b2  = (const float*)d_in[5];
    float* out = (float*)d_out;

    char* ws = (char*)d_ws;
    int* counts = (int*)ws;                       // 32 B (memset 0)
    int* bucket = (int*)(ws + 4096);              // 64 KB
    u16* Ag     = (u16*)(ws + 131072);            // 136 tiles * 64KB*... = 17.0 MiB
    u16* W1p    = (u16*)(ws + 131072 + 136u * 32u * 2048u * 2u);  // 16 MiB

    hipMemsetAsync(counts, 0, NE * sizeof(int), stream);
    k_prep<<<NB / 256, 256, 0, stream>>>(ids, b2, out, counts, bucket);
    k_pack<<<2048 + NE * MTMAX * 2, 256, 0, stream>>>(W1, W1p, X, Ag, counts, bucket);
    k_gemm<<<NE * MTMAX * 8, 256, 0, stream>>>(Ag, W1p, b1, W2, counts, bucket, out);
}

// Round 5
// 171.949 us; speedup vs baseline: 1.0242x; 1.0081x over previous
//
#include <hip/hip_runtime.h>
#include <hip/hip_bf16.h>

#define NB 8192
#define ND 1024
#define NE 8
#define BSTRIDE 2048   // bucket capacity per expert
#define MTMAX 18       // max 64-row tiles per expert (cnt ~1024±30)

typedef unsigned short u16;
typedef __bf16 bf16x8 __attribute__((ext_vector_type(8)));
typedef float f32x4 __attribute__((ext_vector_type(4)));
typedef u16 u16x8 __attribute__((ext_vector_type(8)));
typedef u16 u16x4 __attribute__((ext_vector_type(4)));

__device__ __forceinline__ u16 f2bf(float f) {
    union { float f; unsigned u; } v; v.f = f;
    unsigned r = v.u + 0x7fffu + ((v.u >> 16) & 1u);
    return (u16)(r >> 16);
}

// ---------------- K0: bucket by expert (ballot scatter) + init out with b2 ----------------
__global__ __launch_bounds__(256) void k_prep(const int* __restrict__ ids,
    const float* __restrict__ b2, float* __restrict__ out,
    int* __restrict__ counts, int* __restrict__ bucket)
{
    int t = threadIdx.x;
    int b = blockIdx.x * 256 + t;
    int e = ids[b];
    out[2 * b]     = b2[2 * e];
    out[2 * b + 1] = b2[2 * e + 1];
    int lane = t & 63;
    unsigned long long lt = (1ull << lane) - 1ull;
    int pos = 0;
    #pragma unroll
    for (int ee = 0; ee < NE; ++ee) {
        unsigned long long m = __ballot(e == ee);
        if (m) {
            int leader = __ffsll((long long)m) - 1;
            int r = __popcll(m & lt);
            int base = 0;
            if (e == ee && r == 0) base = atomicAdd(&counts[ee], __popcll(m));
            base = __shfl(base, leader, 64);
            if (e == ee) pos = base + r;
        }
    }
    bucket[e * BSTRIDE + pos] = b;
}

// ---------------- K1: pack W1 -> W1p tiles  AND  X -> Ag gathered tiles ----------------
// Layouts hold the 16B k-slot XOR-swizzled within each 64B row:
//   elem_off(row, kk) = row*32 + ((kk>>3) ^ ((row>>1)&3))*8 + (kk&7)
// so that linear global_load_lds staging + swizzled ds_read is conflict-free.
__global__ __launch_bounds__(256) void k_pack(
    const float* __restrict__ W1, u16* __restrict__ W1p,
    const float* __restrict__ X, u16* __restrict__ Ag,
    const int* __restrict__ counts, const int* __restrict__ bucket)
{
    int bid = blockIdx.x;
    int t = threadIdx.x;
    if (bid < 2048) {
        // W1 [e][k][n] fp32 -> W1p via 64x64 LDS transpose
        __shared__ float s[64][65];
        int e = bid >> 8;
        int tr = ((bid >> 4) & 15) << 6;  // k tile base
        int tc = (bid & 15) << 6;         // n tile base
        const float* src = W1 + (size_t)e * ND * ND;
        #pragma unroll
        for (int i = 0; i < 4; ++i) {
            int idx = i * 256 + t;
            int r = idx >> 4, c4 = (idx & 15) * 4;
            f32x4 v = *(const f32x4*)(src + (size_t)(tr + r) * ND + tc + c4);
            s[c4 + 0][r] = v[0]; s[c4 + 1][r] = v[1];
            s[c4 + 2][r] = v[2]; s[c4 + 3][r] = v[3];
        }
        __syncthreads();
        #pragma unroll
        for (int i = 0; i < 4; ++i) {
            int idx = i * 256 + t;
            int n = idx >> 4, k4 = (idx & 15) * 4;
            int gn = tc + n, gk = tr + k4;
            int nt = gn >> 7, kt = gk >> 5;
            int row = gn & 127, kk = gk & 31;
            u16x4 o;
            o[0] = f2bf(s[n][k4 + 0]); o[1] = f2bf(s[n][k4 + 1]);
            o[2] = f2bf(s[n][k4 + 2]); o[3] = f2bf(s[n][k4 + 3]);
            int off = row * 32 + ((((kk >> 3) ^ ((row >> 1) & 3))) << 3) + (kk & 7);
            *(u16x4*)(W1p + (((size_t)(e * 8 + nt) * 32 + kt) * 4096) + off) = o;
        }
        return;
    }
    // X gather-pack: block = (e, mt, half); 64 rows x 512 k
    __shared__ int sR[64];
    int bid2 = bid - 2048;
    int half = bid2 & 1;
    int g = bid2 >> 1;             // 0..143
    int e = g / MTMAX, mt = g % MTMAX;
    int cnt = counts[e];
    if (mt * 64 >= cnt) return;
    int tb = 0;
    #pragma unroll
    for (int j = 0; j < NE; ++j) if (j < e) tb += (counts[j] + 63) >> 6;
    size_t tbase = (size_t)(tb + mt) * 32 * 2048;
    if (t < 64) {
        int rr = mt * 64 + t;
        sR[t] = bucket[e * BSTRIDE + (rr < cnt ? rr : 0)];
    }
    __syncthreads();
    #pragma unroll 4
    for (int i = 0; i < 32; ++i) {
        int c = i * 256 + t;           // 8192 chunks of 4 fp32
        int r = c >> 7, ck = c & 127;
        int k = half * 512 + ck * 4;
        f32x4 v = *(const f32x4*)(X + (size_t)sR[r] * ND + k);
        u16x4 o;
        o[0] = f2bf(v[0]); o[1] = f2bf(v[1]); o[2] = f2bf(v[2]); o[3] = f2bf(v[3]);
        int kt = k >> 5, kk = k & 31;
        int off = r * 32 + ((((kk >> 3) ^ ((r >> 1) & 3))) << 3) + (kk & 7);
        *(u16x4*)(Ag + tbase + (size_t)kt * 2048 + off) = o;
    }
}

// ---------------- K2: grouped GEMM 64x128 tile (bf16 MFMA) + fused layer-2 epilogue ----------------
#define GLDS16(src, dst) __builtin_amdgcn_global_load_lds( \
    (const __attribute__((address_space(1))) void*)(src), \
    (__attribute__((address_space(3))) void*)(dst), 16, 0, 0)

__global__ __launch_bounds__(256) void k_gemm(
    const u16* __restrict__ Ag, const u16* __restrict__ W1p,
    const float* __restrict__ b1, const float* __restrict__ W2,
    const int* __restrict__ counts, const int* __restrict__ bucket,
    float* __restrict__ out)
{
    __shared__ u16 sA[2][2048];   // 64 x 32 per buffer
    __shared__ u16 sB[2][4096];   // 128 x 32 per buffer
    __shared__ int sRows[64];

    int bid = blockIdx.x;
    int e  = bid & 7;          // expert fastest -> pinned per-XCD L2
    int nt = (bid >> 3) & 7;
    int mt = bid >> 6;         // 0..MTMAX-1

    int cnt = counts[e];
    if (mt * 64 >= cnt) return;
    int rem = cnt - mt * 64;

    int t = threadIdx.x;
    if (t < 64) {
        int r = mt * 64 + t;
        sRows[t] = bucket[e * BSTRIDE + (r < cnt ? r : 0)];
    }
    __syncthreads();

    int tb = 0;
    #pragma unroll
    for (int j = 0; j < NE; ++j) if (j < e) tb += (counts[j] + 63) >> 6;

    int n0 = nt * 128;
    const u16* Abase = Ag + (size_t)(tb + mt) * 32 * 2048 + t * 8;
    const u16* Bbase = W1p + (size_t)(e * 8 + nt) * 32 * 4096 + t * 8;
    int w = t >> 6;
    int l = t & 63;
    int lc = l & 15, kg = l >> 4;
    int wm = (w >> 1) * 32, wn = (w & 1) * 64;
    int kslot = (kg ^ ((lc >> 1) & 3)) * 16;   // swizzled 16B slot (wave-uniform XOR term per lane)

    f32x4 acc[2][4] = {};

    char* A0 = (char*)sA;
    char* B0 = (char*)sB;

    auto stage = [&](int buf, int kt) {
        GLDS16(Abase + (size_t)kt * 2048, A0 + buf * 4096 + w * 1024);
        GLDS16(Bbase + (size_t)kt * 4096, B0 + buf * 8192 + w * 1024);
        GLDS16(Bbase + (size_t)kt * 4096 + 2048, B0 + buf * 8192 + 4096 + w * 1024);
    };

    stage(0, 0);

    #pragma unroll 2
    for (int kt = 0; kt < 32; ++kt) {
        int buf = kt & 1;
        if (kt + 1 < 32) {
            stage(buf ^ 1, kt + 1);
            asm volatile("s_waitcnt vmcnt(3)" ::: "memory");
        } else {
            asm volatile("s_waitcnt vmcnt(0)" ::: "memory");
        }
        asm volatile("s_barrier" ::: "memory");

        const char* Ab = A0 + buf * 4096;
        const char* Bb = B0 + buf * 8192;
        bf16x8 af[2], bfr[4];
        #pragma unroll
        for (int mf = 0; mf < 2; ++mf)
            af[mf] = *(const bf16x8*)(Ab + (wm + mf * 16 + lc) * 64 + kslot);
        #pragma unroll
        for (int nf = 0; nf < 4; ++nf)
            bfr[nf] = *(const bf16x8*)(Bb + (wn + nf * 16 + lc) * 64 + kslot);
        #pragma unroll
        for (int mf = 0; mf < 2; ++mf) {
            #pragma unroll
            for (int nf = 0; nf < 4; ++nf)
                acc[mf][nf] = __builtin_amdgcn_mfma_f32_16x16x32_bf16(af[mf], bfr[nf], acc[mf][nf], 0, 0, 0);
        }
        asm volatile("s_barrier" ::: "memory");
    }

    // fused layer 2: logits[b] += sum_n relu(h + b1) * W2[e][n][:]
    float b1v[4], w20[4], w21[4];
    #pragma unroll
    for (int nf = 0; nf < 4; ++nf) {
        int ncol = n0 + wn + nf * 16 + lc;
        b1v[nf] = b1[e * ND + ncol];
        w20[nf] = W2[((size_t)e * ND + ncol) * 2 + 0];
        w21[nf] = W2[((size_t)e * ND + ncol) * 2 + 1];
    }
    #pragma unroll
    for (int mf = 0; mf < 2; ++mf) {
        #pragma unroll
        for (int r = 0; r < 4; ++r) {
            float s0 = 0.f, s1 = 0.f;
            #pragma unroll
            for (int nf = 0; nf < 4; ++nf) {
                float h = acc[mf][nf][r] + b1v[nf];
                h = fmaxf(h, 0.f);
                s0 += h * w20[nf];
                s1 += h * w21[nf];
            }
            #pragma unroll
            for (int m = 8; m >= 1; m >>= 1) {
                s0 += __shfl_xor(s0, m, 64);
                s1 += __shfl_xor(s1, m, 64);
            }
            int row = wm + mf * 16 + kg * 4 + r;
            if (lc == 0 && row < rem) {
                int b = sRows[row];
                atomicAdd(&out[2 * b], s0);
                atomicAdd(&out[2 * b + 1], s1);
            }
        }
    }
}

extern "C" void kernel_launch(void* const* d_in, const int* in_sizes, int n_in,
                              void* d_out, int out_size, void* d_ws, size_t ws_size,
                              hipStream_t stream)
{
    const float* X   = (const float*)d_in[0];
    const int*   ids = (const int*)d_in[1];
    const float* W1  = (const float*)d_in[2];
    const float* b1  = (const float*)d_in[3];
    const float* W2  = (const float*)d_in[4];
    const float* b2  = (const float*)d_in[5];
    float* out = (float*)d_out;

    char* ws = (char*)d_ws;
    int* counts = (int*)ws;                       // 32 B (memset 0)
    int* bucket = (int*)(ws + 4096);              // 64 KB
    u16* Ag     = (u16*)(ws + 131072);            // packed gathered A tiles
    u16* W1p    = (u16*)(ws + 131072 + 160u * 32u * 2048u * 2u);  // packed W1 tiles

    hipMemsetAsync(counts, 0, NE * sizeof(int), stream);
    k_prep<<<NB / 256, 256, 0, stream>>>(ids, b2, out, counts, bucket);
    k_pack<<<2048 + NE * MTMAX * 2, 256, 0, stream>>>(W1, W1p, X, Ag, counts, bucket);
    k_gemm<<<NE * MTMAX * 8, 256, 0, stream>>>(Ag, W1p, b1, W2, counts, bucket, out);
}